// Round 9
// baseline (125.662 us; speedup 1.0000x reference)
//
#include <hip/hip_runtime.h>
#include <stdint.h>

typedef __bf16 bf16x8 __attribute__((ext_vector_type(8)));
typedef uint16_t u16x8 __attribute__((ext_vector_type(8)));
typedef float f32x4 __attribute__((ext_vector_type(4)));

#define DEV static __device__ __forceinline__

DEV uint16_t f2bf(float f) {
  union { float f; uint32_t u; } v; v.f = f;
  return (uint16_t)((v.u + 0x8000u) >> 16);
}
DEV float bf2f(uint16_t h) {
  union { uint32_t u; float f; } v; v.u = ((uint32_t)h) << 16;
  return v.f;
}

#define GLOAD_LDS16(g, l)                                                     \
  __builtin_amdgcn_global_load_lds(                                           \
      (__attribute__((address_space(1))) void*)(g),                           \
      (__attribute__((address_space(3))) void*)(l), 16, 0, 0)

// ---------------- fp32 -> bf16 convert ----------------
__global__ void k_conv(const float* __restrict__ src, uint16_t* __restrict__ dst, int n) {
  int i = blockIdx.x * blockDim.x + threadIdx.x;
  int stride = gridDim.x * blockDim.x;
  for (; i < n; i += stride) dst[i] = f2bf(src[i]);
}

// ---------------- mod = silu(cond) @ ada_w^T + ada_b  (4 x 3072) ----------------
__global__ void k_mod(const float* __restrict__ cond, const float* __restrict__ ada_w,
                      const float* __restrict__ ada_b, float* __restrict__ mod) {
  int w = threadIdx.x >> 6, lane = threadIdx.x & 63;
  int gid = blockIdx.x * 4 + w;
  int b = gid / 3072, j = gid - b * 3072;
  const float* cw = cond + b * 1024;
  const float* aw = ada_w + (size_t)j * 1024;
  float sum = 0.f;
  for (int i = 0; i < 16; ++i) {
    int f = lane + (i << 6);
    float c = cw[f];
    float sc = c / (1.f + __expf(-c));
    sum += sc * aw[f];
  }
  for (int m = 32; m; m >>= 1) sum += __shfl_xor(sum, m, 64);
  if (lane == 0) mod[b * 3072 + j] = sum + ada_b[j];
}

// ---------------- RMSNorm + modulate -> xm bf16 (4096 x 1024) ----------------
__global__ void k_norm_mod(const float* __restrict__ x, const float* __restrict__ norm_scale,
                           const float* __restrict__ mod, uint16_t* __restrict__ xm) {
  int row = blockIdx.x;
  int b = row >> 10;
  const float* xr = x + (size_t)row * 1024;
  const float* shiftp = mod + b * 3072;
  const float* scalep = shiftp + 1024;
  int t = threadIdx.x;
  float v[4];
  float s = 0.f;
  for (int i = 0; i < 4; ++i) { v[i] = xr[t + (i << 8)]; s += v[i] * v[i]; }
  for (int m = 32; m; m >>= 1) s += __shfl_xor(s, m, 64);
  __shared__ float red[4];
  if ((t & 63) == 0) red[t >> 6] = s;
  __syncthreads();
  s = red[0] + red[1] + red[2] + red[3];
  float inv = rsqrtf(s * (1.f / 1024.f) + 1e-6f);
  uint16_t* xo = xm + (size_t)row * 1024;
  for (int i = 0; i < 4; ++i) {
    int c = t + (i << 8);
    float val = v[i] * inv * norm_scale[c];
    val = val * (1.f + scalep[c]) + shiftp[c];
    xo[c] = f2bf(val);
  }
}

// ---------------- QKV GEMM with fused q/k-norm + RoPE + V-transpose epilogue -------
// r4 128x128/BK=32 main loop (proven). Wave tile = 64 rows x 64 cols = one head
// exactly (col0 % 64 == 0). Blocks are head-type-pure: bn 0-7 q, 8-15 k, 16-23 v.
// q/k: rsum via per-lane sum + shfl_xor(1,2,4,8) over the 16 lanes of a row;
// RoPE pairs (d,d+16) = (n=0,n=1) same lane. v: LDS transpose reusing As/Bs
// (XOR swizzle [d][sp^((d&7)<<3)], 2 waves/round) -> coalesced Vt row stores.
__global__ __launch_bounds__(256) void k_gemmqkv(
    const uint16_t* __restrict__ A, const uint16_t* __restrict__ B,
    const float* __restrict__ pos, const float* __restrict__ attn_scale,
    const float* __restrict__ freqs, uint16_t* __restrict__ Qb,
    uint16_t* __restrict__ Kb, uint16_t* __restrict__ Vt) {
  constexpr int K = 1024;
  __shared__ uint16_t As[128 * 32];
  __shared__ uint16_t Bs[128 * 32];
  int t = threadIdx.x;
  int lane = t & 63;
  int w = t >> 6, wr = w >> 1, wc = w & 1;
  int bm = blockIdx.y, bn = blockIdx.x;
  f32x4 acc[4][4] = {};
  const size_t a_base = (size_t)(bm * 128) * K;
  const size_t b_base = (size_t)(bn * 128) * K;
  int r = t >> 2, cch = t & 3;
  for (int kt = 0; kt < K / 32; ++kt) {
    __syncthreads();
#pragma unroll
    for (int i = 0; i < 2; ++i) {
      int rr = r + (i << 6);
      int cs = (cch ^ ((rr >> 1) & 3)) << 3;
      GLOAD_LDS16(A + a_base + (size_t)rr * K + kt * 32 + cs, As + rr * 32 + (cch << 3));
      GLOAD_LDS16(B + b_base + (size_t)rr * K + kt * 32 + cs, Bs + rr * 32 + (cch << 3));
    }
    __syncthreads();
    bf16x8 af[4], bfr[4];
    int lq = lane >> 4;
#pragma unroll
    for (int m = 0; m < 4; ++m) {
      int R = wr * 64 + m * 16 + (lane & 15);
      af[m] = *reinterpret_cast<const bf16x8*>(&As[R * 32 + ((lq ^ ((R >> 1) & 3)) << 3)]);
    }
#pragma unroll
    for (int n = 0; n < 4; ++n) {
      int R = wc * 64 + n * 16 + (lane & 15);
      bfr[n] = *reinterpret_cast<const bf16x8*>(&Bs[R * 32 + ((lq ^ ((R >> 1) & 3)) << 3)]);
    }
#pragma unroll
    for (int m = 0; m < 4; ++m)
#pragma unroll
      for (int n = 0; n < 4; ++n)
        acc[m][n] = __builtin_amdgcn_mfma_f32_16x16x32_bf16(af[m], bfr[n], acc[m][n], 0, 0, 0);
  }
  // ---- fused epilogue ----
  int c = bn * 2 + wc;   // head-chunk 0..47
  int sec = c >> 4;      // 0 q, 1 k, 2 v
  int h = c & 15;
  int i = lane & 15, g = lane >> 4;
  int row0 = bm * 128 + wr * 64;
  __syncthreads();  // all LDS reads of main loop done before any reuse
  if (sec < 2) {
    uint16_t* dst = sec ? Kb : Qb;
    float ss = sqrtf(attn_scale[h]);
#pragma unroll
    for (int m = 0; m < 4; ++m)
#pragma unroll
      for (int rr = 0; rr < 4; ++rr) {
        int R = row0 + m * 16 + g * 4 + rr;  // global row = b*1024 + sp
        float v0 = acc[m][0][rr], v1 = acc[m][1][rr];
        float v2 = acc[m][2][rr], v3 = acc[m][3][rr];
        float p = v0 * v0 + v1 * v1 + v2 * v2 + v3 * v3;
        p += __shfl_xor(p, 1, 64); p += __shfl_xor(p, 2, 64);
        p += __shfl_xor(p, 4, 64); p += __shfl_xor(p, 8, 64);
        float sc = ss * rsqrtf(p + 1e-6f);
        v0 *= sc; v1 *= sc; v2 *= sc; v3 *= sc;
        float th = ((i < 8) ? pos[2 * R] : pos[2 * R + 1]) * freqs[h * 8 + (i & 7)];
        float sn, csn;
        __sincosf(th, &sn, &csn);
        float y0 = v0 * csn - v1 * sn;
        float y1 = v1 * csn + v0 * sn;
        size_t base = (((size_t)((R >> 10) * 16 + h)) * 1024 + (R & 1023)) * 64 + i;
        dst[base] = f2bf(y0);
        dst[base + 16] = f2bf(y1);
        dst[base + 32] = f2bf(v2);
        dst[base + 48] = f2bf(v3);
      }
    __syncthreads();
    __syncthreads();
    __syncthreads();
    __syncthreads();  // match v-path barrier count (2 rounds x 2)
  } else {
    uint16_t* vt = wc ? Bs : As;  // 8KB = 64x64 u16 per wave, 2 waves/round
    int b = row0 >> 10, spbase = row0 & 1023;
    size_t vrow = ((size_t)(b * 16 + h)) * 64;
#pragma unroll
    for (int rnd = 0; rnd < 2; ++rnd) {
      if (wr == rnd) {
#pragma unroll
        for (int m = 0; m < 4; ++m)
#pragma unroll
          for (int n = 0; n < 4; ++n)
#pragma unroll
            for (int rr = 0; rr < 4; ++rr) {
              int sl = m * 16 + g * 4 + rr;
              int d = n * 16 + i;
              vt[d * 64 + (sl ^ ((d & 7) << 3))] = f2bf(acc[m][n][rr]);
            }
      }
      __syncthreads();
      if (wr == rnd) {
#pragma unroll
        for (int p = 0; p < 4; ++p) {
          int d = p * 16 + (lane >> 2);
          int s0 = (lane & 3) * 16;
          int xr = (d & 7) << 3;
          u16x8 va = *reinterpret_cast<const u16x8*>(&vt[d * 64 + (s0 ^ xr)]);
          u16x8 vb = *reinterpret_cast<const u16x8*>(&vt[d * 64 + ((s0 + 8) ^ xr)]);
          size_t o = (vrow + d) * 1024 + spbase + s0;
          *reinterpret_cast<u16x8*>(Vt + o) = va;
          *reinterpret_cast<u16x8*>(Vt + o + 8) = vb;
        }
      }
      __syncthreads();
    }
  }
}

// ---------------- out GEMM: 128x128 r4 structure, skip+gate epilogue ----------------
template <int N, int EPI>
__global__ __launch_bounds__(256) void k_gemm(const uint16_t* __restrict__ A,
                                              const uint16_t* __restrict__ B,
                                              uint16_t* __restrict__ Cbf,
                                              const float* __restrict__ skip,
                                              const float* __restrict__ modp,
                                              float* __restrict__ Cout) {
  constexpr int K = 1024;
  __shared__ uint16_t As[128 * 32];
  __shared__ uint16_t Bs[128 * 32];
  int t = threadIdx.x;
  int lane = t & 63;
  int w = t >> 6, wr = w >> 1, wc = w & 1;
  int bm = blockIdx.y, bn = blockIdx.x;
  f32x4 acc[4][4] = {};
  const size_t a_base = (size_t)(bm * 128) * K;
  const size_t b_base = (size_t)(bn * 128) * K;
  int r = t >> 2, cch = t & 3;
  for (int kt = 0; kt < K / 32; ++kt) {
    __syncthreads();
#pragma unroll
    for (int i = 0; i < 2; ++i) {
      int rr = r + (i << 6);
      int cs = (cch ^ ((rr >> 1) & 3)) << 3;
      GLOAD_LDS16(A + a_base + (size_t)rr * K + kt * 32 + cs, As + rr * 32 + (cch << 3));
      GLOAD_LDS16(B + b_base + (size_t)rr * K + kt * 32 + cs, Bs + rr * 32 + (cch << 3));
    }
    __syncthreads();
    bf16x8 af[4], bfr[4];
    int lq = lane >> 4;
#pragma unroll
    for (int m = 0; m < 4; ++m) {
      int R = wr * 64 + m * 16 + (lane & 15);
      af[m] = *reinterpret_cast<const bf16x8*>(&As[R * 32 + ((lq ^ ((R >> 1) & 3)) << 3)]);
    }
#pragma unroll
    for (int n = 0; n < 4; ++n) {
      int R = wc * 64 + n * 16 + (lane & 15);
      bfr[n] = *reinterpret_cast<const bf16x8*>(&Bs[R * 32 + ((lq ^ ((R >> 1) & 3)) << 3)]);
    }
#pragma unroll
    for (int m = 0; m < 4; ++m)
#pragma unroll
      for (int n = 0; n < 4; ++n)
        acc[m][n] = __builtin_amdgcn_mfma_f32_16x16x32_bf16(af[m], bfr[n], acc[m][n], 0, 0, 0);
  }
  int row0 = bm * 128 + wr * 64;
  int col0 = bn * 128 + wc * 64;
#pragma unroll
  for (int m = 0; m < 4; ++m)
#pragma unroll
    for (int n = 0; n < 4; ++n)
#pragma unroll
      for (int rr = 0; rr < 4; ++rr) {
        int R = row0 + m * 16 + ((lane >> 4) << 2) + rr;
        int C = col0 + n * 16 + (lane & 15);
        float v = acc[m][n][rr];
        if (EPI == 0) {
          Cbf[(size_t)R * N + C] = f2bf(v);
        } else {
          float g = modp[(R >> 10) * 3072 + 2048 + C];
          Cout[(size_t)R * N + C] = skip[(size_t)R * N + C] + g * v;
        }
      }
}

// ---------------- flash attention: 4 waves x 32 q-rows ----------------
__global__ __launch_bounds__(256) void k_attn(const uint16_t* __restrict__ Qb,
                                              const uint16_t* __restrict__ Kb,
                                              const uint16_t* __restrict__ Vt,
                                              uint16_t* __restrict__ obuf) {
  __shared__ uint16_t Ks[64 * 64];
  __shared__ uint16_t Vs[64 * 64];
  __shared__ uint16_t Ps[4][32 * 88];
  int t = threadIdx.x, lane = t & 63, w = t >> 6;  // w: 0..3
  int qt = blockIdx.y, bh = blockIdx.x;
  int b = bh >> 4, h = bh & 15;
  int klo = (lane >> 4) << 3;
  bf16x8 qf[2][2];
#pragma unroll
  for (int qs = 0; qs < 2; ++qs) {
    int qrow = qt * 128 + w * 32 + qs * 16 + (lane & 15);
    const uint16_t* qptr = Qb + ((size_t)bh * 1024 + qrow) * 64 + klo;
    qf[qs][0] = *reinterpret_cast<const bf16x8*>(qptr);
    qf[qs][1] = *reinterpret_cast<const bf16x8*>(qptr + 32);
  }
  f32x4 oacc[2][4] = {};
  float denom[2][4] = {};
  const size_t kbase = (size_t)bh * 1024 * 64;
  const size_t vbase = (size_t)bh * 64 * 1024;
  for (int kt = 0; kt < 16; ++kt) {
    __syncthreads();
#pragma unroll
    for (int i = 0; i < 2; ++i) {
      int slot = t + (i << 8);
      int row = slot >> 3;
      int ce = ((slot & 7) ^ (row & 7)) << 3;
      GLOAD_LDS16(Kb + kbase + (size_t)(kt * 64 + row) * 64 + ce, Ks + slot * 8);
      GLOAD_LDS16(Vt + vbase + (size_t)row * 1024 + kt * 64 + ce, Vs + slot * 8);
    }
    __syncthreads();
    f32x4 s[2][4];
#pragma unroll
    for (int n = 0; n < 4; ++n) {
      int row = n * 16 + (lane & 15);
      int sw = (row & 7) << 3;
      bf16x8 kf0 = *reinterpret_cast<const bf16x8*>(&Ks[row * 64 + (klo ^ sw)]);
      bf16x8 kf1 = *reinterpret_cast<const bf16x8*>(&Ks[row * 64 + ((32 + klo) ^ sw)]);
#pragma unroll
      for (int qs = 0; qs < 2; ++qs) {
        f32x4 z = {};
        z = __builtin_amdgcn_mfma_f32_16x16x32_bf16(qf[qs][0], kf0, z, 0, 0, 0);
        z = __builtin_amdgcn_mfma_f32_16x16x32_bf16(qf[qs][1], kf1, z, 0, 0, 0);
        s[qs][n] = z;
      }
    }
#pragma unroll
    for (int qs = 0; qs < 2; ++qs)
#pragma unroll
      for (int n = 0; n < 4; ++n)
#pragma unroll
        for (int rr = 0; rr < 4; ++rr) {
          float p = __expf(s[qs][n][rr]);
          denom[qs][rr] += p;
          Ps[w][(qs * 16 + ((lane >> 4) << 2) + rr) * 88 + n * 16 + (lane & 15)] = f2bf(p);
        }
    bf16x8 pa[2][2];
#pragma unroll
    for (int qs = 0; qs < 2; ++qs) {
      pa[qs][0] = *reinterpret_cast<const bf16x8*>(&Ps[w][(qs * 16 + (lane & 15)) * 88 + klo]);
      pa[qs][1] = *reinterpret_cast<const bf16x8*>(&Ps[w][(qs * 16 + (lane & 15)) * 88 + 32 + klo]);
    }
#pragma unroll
    for (int dt = 0; dt < 4; ++dt) {
      int row = dt * 16 + (lane & 15);
      int sw = (row & 7) << 3;
      bf16x8 vf0 = *reinterpret_cast<const bf16x8*>(&Vs[row * 64 + (klo ^ sw)]);
      bf16x8 vf1 = *reinterpret_cast<const bf16x8*>(&Vs[row * 64 + ((32 + klo) ^ sw)]);
#pragma unroll
      for (int qs = 0; qs < 2; ++qs) {
        oacc[qs][dt] = __builtin_amdgcn_mfma_f32_16x16x32_bf16(pa[qs][0], vf0, oacc[qs][dt], 0, 0, 0);
        oacc[qs][dt] = __builtin_amdgcn_mfma_f32_16x16x32_bf16(pa[qs][1], vf1, oacc[qs][dt], 0, 0, 0);
      }
    }
  }
#pragma unroll
  for (int qs = 0; qs < 2; ++qs)
#pragma unroll
    for (int rr = 0; rr < 4; ++rr)
      for (int msk = 8; msk; msk >>= 1) denom[qs][rr] += __shfl_xor(denom[qs][rr], msk, 64);
#pragma unroll
  for (int qs = 0; qs < 2; ++qs)
#pragma unroll
    for (int rr = 0; rr < 4; ++rr) {
      float rinv = 1.f / denom[qs][rr];
      int sp = qt * 128 + w * 32 + qs * 16 + ((lane >> 4) << 2) + rr;
      size_t orow = ((size_t)b * 1024 + sp) * 1024 + h * 64;
#pragma unroll
      for (int dt = 0; dt < 4; ++dt)
        obuf[orow + dt * 16 + (lane & 15)] = f2bf(oacc[qs][dt][rr] * rinv);
    }
}

extern "C" void kernel_launch(void* const* d_in, const int* in_sizes, int n_in,
                              void* d_out, int out_size, void* d_ws, size_t ws_size,
                              hipStream_t stream) {
  const float* x = (const float*)d_in[0];
  const float* pos = (const float*)d_in[1];
  const float* cond = (const float*)d_in[2];
  const float* norm_scale = (const float*)d_in[3];
  const float* ada_w = (const float*)d_in[4];
  const float* ada_b = (const float*)d_in[5];
  const float* qkv_w = (const float*)d_in[6];
  const float* attn_scale = (const float*)d_in[7];
  const float* out_w = (const float*)d_in[8];
  const float* freqs = (const float*)d_in[9];
  float* out = (float*)d_out;
  char* ws = (char*)d_ws;
  float* mod = (float*)(ws + 0);                  //  49,152
  uint16_t* xm = (uint16_t*)(ws + 65536);         //   8 MB
  uint16_t* qkvw_bf = (uint16_t*)(ws + 8454144);  //   6 MB
  uint16_t* outw_bf = (uint16_t*)(ws + 14745600); //   2 MB
  uint16_t* Qb = (uint16_t*)(ws + 42008576);      //   8 MB
  uint16_t* Kb = (uint16_t*)(ws + 50397184);      //   8 MB
  uint16_t* Vt = (uint16_t*)(ws + 58785792);      //   8 MB
  uint16_t* obuf = (uint16_t*)(ws + 67174400);    //   8 MB

  k_conv<<<dim3(1024), dim3(256), 0, stream>>>(qkv_w, qkvw_bf, 3 * 1024 * 1024);
  k_conv<<<dim3(512), dim3(256), 0, stream>>>(out_w, outw_bf, 1024 * 1024);
  k_mod<<<dim3(3072), dim3(256), 0, stream>>>(cond, ada_w, ada_b, mod);
  k_norm_mod<<<dim3(4096), dim3(256), 0, stream>>>(x, norm_scale, mod, xm);
  k_gemmqkv<<<dim3(24, 32), dim3(256), 0, stream>>>(xm, qkvw_bf, pos, attn_scale, freqs, Qb, Kb, Vt);
  k_attn<<<dim3(64, 8), dim3(256), 0, stream>>>(Qb, Kb, Vt, obuf);
  k_gemm<1024, 1><<<dim3(8, 32), dim3(256), 0, stream>>>(obuf, outw_bf, nullptr, x, mod, out);
}

// Round 10
// 118.189 us; speedup vs baseline: 1.0632x; 1.0632x over previous
//
#include <hip/hip_runtime.h>
#include <stdint.h>

typedef __bf16 bf16x8 __attribute__((ext_vector_type(8)));
typedef uint16_t u16x8 __attribute__((ext_vector_type(8)));
typedef uint16_t u16x4 __attribute__((ext_vector_type(4)));
typedef float f32x4 __attribute__((ext_vector_type(4)));

#define DEV static __device__ __forceinline__

DEV uint16_t f2bf(float f) {
  union { float f; uint32_t u; } v; v.f = f;
  return (uint16_t)((v.u + 0x8000u) >> 16);
}
DEV float bf2f(uint16_t h) {
  union { uint32_t u; float f; } v; v.u = ((uint32_t)h) << 16;
  return v.f;
}

#define GLOAD_LDS16(g, l)                                                     \
  __builtin_amdgcn_global_load_lds(                                           \
      (__attribute__((address_space(1))) void*)(g),                           \
      (__attribute__((address_space(3))) void*)(l), 16, 0, 0)

// ---------------- fused prep: bf16 weight converts + mod GEMV (one launch) --------
DEV void conv4(const float* __restrict__ src, uint16_t* __restrict__ dst, int n4,
               int tid, int nth) {
  const float4* s4 = (const float4*)src;
  for (int i = tid; i < n4; i += nth) {
    float4 v = s4[i];
    u16x4 o;
    o[0] = f2bf(v.x); o[1] = f2bf(v.y); o[2] = f2bf(v.z); o[3] = f2bf(v.w);
    *reinterpret_cast<u16x4*>(dst + (size_t)i * 4) = o;
  }
}

__global__ __launch_bounds__(256) void k_prep(
    const float* __restrict__ qkv_w, uint16_t* __restrict__ qkvw_bf,
    const float* __restrict__ out_w, uint16_t* __restrict__ outw_bf,
    const float* __restrict__ cond, const float* __restrict__ ada_w,
    const float* __restrict__ ada_b, float* __restrict__ mod) {
  int blk = blockIdx.x, t = threadIdx.x;
  if (blk < 3072) {  // mod = silu(cond) @ ada_w^T + ada_b (4 x 3072)
    int w = t >> 6, lane = t & 63;
    int gid = blk * 4 + w;
    int b = gid / 3072, j = gid - b * 3072;
    const float* cw = cond + b * 1024;
    const float* aw = ada_w + (size_t)j * 1024;
    float sum = 0.f;
    for (int i = 0; i < 16; ++i) {
      int f = lane + (i << 6);
      float c = cw[f];
      sum += (c / (1.f + __expf(-c))) * aw[f];
    }
    for (int m = 32; m; m >>= 1) sum += __shfl_xor(sum, m, 64);
    if (lane == 0) mod[b * 3072 + j] = sum + ada_b[j];
  } else if (blk < 3072 + 768) {  // qkv_w: 3M elems = 786432 float4
    conv4(qkv_w, qkvw_bf, 786432, (blk - 3072) * 256 + t, 768 * 256);
  } else {  // out_w: 1M elems = 262144 float4
    conv4(out_w, outw_bf, 262144, (blk - 3840) * 256 + t, 256 * 256);
  }
}

// ---------------- RMSNorm + modulate -> xm bf16 (4096 x 1024) ----------------
__global__ void k_norm_mod(const float* __restrict__ x, const float* __restrict__ norm_scale,
                           const float* __restrict__ mod, uint16_t* __restrict__ xm) {
  int row = blockIdx.x;
  int b = row >> 10;
  const float* xr = x + (size_t)row * 1024;
  const float* shiftp = mod + b * 3072;
  const float* scalep = shiftp + 1024;
  int t = threadIdx.x;
  float v[4];
  float s = 0.f;
  for (int i = 0; i < 4; ++i) { v[i] = xr[t + (i << 8)]; s += v[i] * v[i]; }
  for (int m = 32; m; m >>= 1) s += __shfl_xor(s, m, 64);
  __shared__ float red[4];
  if ((t & 63) == 0) red[t >> 6] = s;
  __syncthreads();
  s = red[0] + red[1] + red[2] + red[3];
  float inv = rsqrtf(s * (1.f / 1024.f) + 1e-6f);
  uint16_t* xo = xm + (size_t)row * 1024;
  for (int i = 0; i < 4; ++i) {
    int c = t + (i << 8);
    float val = v[i] * inv * norm_scale[c];
    val = val * (1.f + scalep[c]) + shiftp[c];
    xo[c] = f2bf(val);
  }
}

// ---------------- GEMM: 128x128 r4 structure (proven 124.4 us config) ----------------
template <int N, int EPI>
__global__ __launch_bounds__(256) void k_gemm(const uint16_t* __restrict__ A,
                                              const uint16_t* __restrict__ B,
                                              uint16_t* __restrict__ Cbf,
                                              const float* __restrict__ skip,
                                              const float* __restrict__ modp,
                                              float* __restrict__ Cout) {
  constexpr int K = 1024;
  __shared__ uint16_t As[128 * 32];
  __shared__ uint16_t Bs[128 * 32];
  int t = threadIdx.x;
  int lane = t & 63;
  int w = t >> 6, wr = w >> 1, wc = w & 1;
  int bm = blockIdx.y, bn = blockIdx.x;
  f32x4 acc[4][4] = {};
  const size_t a_base = (size_t)(bm * 128) * K;
  const size_t b_base = (size_t)(bn * 128) * K;
  int r = t >> 2, cch = t & 3;
  for (int kt = 0; kt < K / 32; ++kt) {
    __syncthreads();
#pragma unroll
    for (int i = 0; i < 2; ++i) {
      int rr = r + (i << 6);
      int cs = (cch ^ ((rr >> 1) & 3)) << 3;
      GLOAD_LDS16(A + a_base + (size_t)rr * K + kt * 32 + cs, As + rr * 32 + (cch << 3));
      GLOAD_LDS16(B + b_base + (size_t)rr * K + kt * 32 + cs, Bs + rr * 32 + (cch << 3));
    }
    __syncthreads();
    bf16x8 af[4], bfr[4];
    int lq = lane >> 4;
#pragma unroll
    for (int m = 0; m < 4; ++m) {
      int R = wr * 64 + m * 16 + (lane & 15);
      af[m] = *reinterpret_cast<const bf16x8*>(&As[R * 32 + ((lq ^ ((R >> 1) & 3)) << 3)]);
    }
#pragma unroll
    for (int n = 0; n < 4; ++n) {
      int R = wc * 64 + n * 16 + (lane & 15);
      bfr[n] = *reinterpret_cast<const bf16x8*>(&Bs[R * 32 + ((lq ^ ((R >> 1) & 3)) << 3)]);
    }
#pragma unroll
    for (int m = 0; m < 4; ++m)
#pragma unroll
      for (int n = 0; n < 4; ++n)
        acc[m][n] = __builtin_amdgcn_mfma_f32_16x16x32_bf16(af[m], bfr[n], acc[m][n], 0, 0, 0);
  }
  int row0 = bm * 128 + wr * 64;
  int col0 = bn * 128 + wc * 64;
#pragma unroll
  for (int m = 0; m < 4; ++m)
#pragma unroll
    for (int n = 0; n < 4; ++n)
#pragma unroll
      for (int rr = 0; rr < 4; ++rr) {
        int R = row0 + m * 16 + ((lane >> 4) << 2) + rr;
        int C = col0 + n * 16 + (lane & 15);
        float v = acc[m][n][rr];
        if (EPI == 0) {
          Cbf[(size_t)R * N + C] = f2bf(v);
        } else {
          float g = modp[(R >> 10) * 3072 + 2048 + C];
          Cout[(size_t)R * N + C] = skip[(size_t)R * N + C] + g * v;
        }
      }
}

// ---------------- q/k cosine-norm + RoPE + attention layouts ----------------
__global__ __launch_bounds__(256) void k_qkvpost(
    const uint16_t* __restrict__ qkv, const float* __restrict__ pos,
    const float* __restrict__ freqs, const float* __restrict__ attn_scale,
    uint16_t* __restrict__ Qb, uint16_t* __restrict__ Kb, uint16_t* __restrict__ Vt) {
  __shared__ uint16_t vtile[64 * 66];
  int t = threadIdx.x;
  int st = blockIdx.x, bh = blockIdx.y;
  int b = bh >> 4, h = bh & 15;
  int r = t >> 2;
  int s = t & 3;
  int sp = st * 64 + r;
  size_t m = (size_t)b * 1024 + sp;
  const uint16_t* basep = qkv + m * 3072 + h * 64 + s * 16;
  bf16x8 q0 = *reinterpret_cast<const bf16x8*>(basep);
  bf16x8 q1 = *reinterpret_cast<const bf16x8*>(basep + 8);
  bf16x8 k0 = *reinterpret_cast<const bf16x8*>(basep + 1024);
  bf16x8 k1 = *reinterpret_cast<const bf16x8*>(basep + 1032);
  u16x8 v0 = *reinterpret_cast<const u16x8*>(basep + 2048);
  u16x8 v1 = *reinterpret_cast<const u16x8*>(basep + 2056);
  float qv[16], kv[16];
#pragma unroll
  for (int i = 0; i < 8; ++i) {
    qv[i] = (float)q0[i]; qv[8 + i] = (float)q1[i];
    kv[i] = (float)k0[i]; kv[8 + i] = (float)k1[i];
  }
  float sq = 0.f, sk = 0.f;
#pragma unroll
  for (int i = 0; i < 16; ++i) { sq += qv[i] * qv[i]; sk += kv[i] * kv[i]; }
  sq += __shfl_xor(sq, 1, 64); sq += __shfl_xor(sq, 2, 64);
  sk += __shfl_xor(sk, 1, 64); sk += __shfl_xor(sk, 2, 64);
  float ss = sqrtf(attn_scale[h]);
  float qs = ss * rsqrtf(sq + 1e-6f);
  float ks = ss * rsqrtf(sk + 1e-6f);
#pragma unroll
  for (int i = 0; i < 16; ++i) { qv[i] *= qs; kv[i] *= ks; }
  float p0 = pos[m * 2], p1 = pos[m * 2 + 1];
  float sgn = (s == 0) ? -1.f : 1.f;
#pragma unroll
  for (int i = 0; i < 16; ++i) {
    float pq = __shfl_xor(qv[i], 1, 64);
    float pk = __shfl_xor(kv[i], 1, 64);
    if (s < 2) {
      float th = ((i < 8) ? p0 : p1) * freqs[h * 8 + (i & 7)];
      float sn, cs;
      __sincosf(th, &sn, &cs);
      qv[i] = qv[i] * cs + sgn * pq * sn;
      kv[i] = kv[i] * cs + sgn * pk * sn;
    }
  }
  bf16x8 qo0, qo1, ko0, ko1;
#pragma unroll
  for (int i = 0; i < 8; ++i) {
    qo0[i] = (__bf16)qv[i]; qo1[i] = (__bf16)qv[8 + i];
    ko0[i] = (__bf16)kv[i]; ko1[i] = (__bf16)kv[8 + i];
  }
  size_t qkb = ((size_t)bh * 1024 + sp) * 64 + s * 16;
  *reinterpret_cast<bf16x8*>(Qb + qkb) = qo0;
  *reinterpret_cast<bf16x8*>(Qb + qkb + 8) = qo1;
  *reinterpret_cast<bf16x8*>(Kb + qkb) = ko0;
  *reinterpret_cast<bf16x8*>(Kb + qkb + 8) = ko1;
#pragma unroll
  for (int i = 0; i < 8; ++i) {
    vtile[(s * 16 + i) * 66 + r] = v0[i];
    vtile[(s * 16 + 8 + i) * 66 + r] = v1[i];
  }
  __syncthreads();
  int d = t >> 2, c = t & 3;
  u16x8 w0, w1;
#pragma unroll
  for (int i = 0; i < 8; ++i) {
    w0[i] = vtile[d * 66 + c * 16 + i];
    w1[i] = vtile[d * 66 + c * 16 + 8 + i];
  }
  size_t vb = ((size_t)bh * 64 + d) * 1024 + st * 64 + c * 16;
  *reinterpret_cast<u16x8*>(Vt + vb) = w0;
  *reinterpret_cast<u16x8*>(Vt + vb + 8) = w1;
}

// ---------------- flash attention (r4: 8 waves x 16 q, no max-sub) ----------------
__global__ __launch_bounds__(512) void k_attn(const uint16_t* __restrict__ Qb,
                                              const uint16_t* __restrict__ Kb,
                                              const uint16_t* __restrict__ Vt,
                                              uint16_t* __restrict__ obuf) {
  __shared__ uint16_t Ks[64 * 64];
  __shared__ uint16_t Vs[64 * 64];
  __shared__ uint16_t Ps[8][16 * 88];
  int t = threadIdx.x, lane = t & 63, w = t >> 6;
  int qt = blockIdx.y, bh = blockIdx.x;
  int b = bh >> 4, h = bh & 15;
  int qrow = qt * 128 + w * 16 + (lane & 15);
  int klo = (lane >> 4) << 3;
  const uint16_t* qptr = Qb + ((size_t)bh * 1024 + qrow) * 64 + klo;
  bf16x8 qf0 = *reinterpret_cast<const bf16x8*>(qptr);
  bf16x8 qf1 = *reinterpret_cast<const bf16x8*>(qptr + 32);
  f32x4 oacc[4] = {};
  float denom[4] = {0.f, 0.f, 0.f, 0.f};
  const size_t kbase = (size_t)bh * 1024 * 64;
  const size_t vbase = (size_t)bh * 64 * 1024;
  for (int kt = 0; kt < 16; ++kt) {
    __syncthreads();
    {
      int row = t >> 3;
      int ce = ((t & 7) ^ (row & 7)) << 3;
      GLOAD_LDS16(Kb + kbase + (size_t)(kt * 64 + row) * 64 + ce, Ks + t * 8);
      GLOAD_LDS16(Vt + vbase + (size_t)row * 1024 + kt * 64 + ce, Vs + t * 8);
    }
    __syncthreads();
    bf16x8 pa0, pa1;
    {
      f32x4 s[4];
      for (int n = 0; n < 4; ++n) {
        int row = n * 16 + (lane & 15);
        int sw = (row & 7) << 3;
        bf16x8 kf0 = *reinterpret_cast<const bf16x8*>(&Ks[row * 64 + (klo ^ sw)]);
        bf16x8 kf1 = *reinterpret_cast<const bf16x8*>(&Ks[row * 64 + ((32 + klo) ^ sw)]);
        f32x4 z = {};
        z = __builtin_amdgcn_mfma_f32_16x16x32_bf16(qf0, kf0, z, 0, 0, 0);
        z = __builtin_amdgcn_mfma_f32_16x16x32_bf16(qf1, kf1, z, 0, 0, 0);
        s[n] = z;
      }
      for (int n = 0; n < 4; ++n)
        for (int rr = 0; rr < 4; ++rr) {
          float p = __expf(s[n][rr]);
          denom[rr] += p;
          Ps[w][(((lane >> 4) << 2) + rr) * 88 + n * 16 + (lane & 15)] = f2bf(p);
        }
      pa0 = *reinterpret_cast<const bf16x8*>(&Ps[w][(lane & 15) * 88 + klo]);
      pa1 = *reinterpret_cast<const bf16x8*>(&Ps[w][(lane & 15) * 88 + 32 + klo]);
    }
    for (int dt = 0; dt < 4; ++dt) {
      int row = dt * 16 + (lane & 15);
      int sw = (row & 7) << 3;
      bf16x8 vf0 = *reinterpret_cast<const bf16x8*>(&Vs[row * 64 + (klo ^ sw)]);
      bf16x8 vf1 = *reinterpret_cast<const bf16x8*>(&Vs[row * 64 + ((32 + klo) ^ sw)]);
      oacc[dt] = __builtin_amdgcn_mfma_f32_16x16x32_bf16(pa0, vf0, oacc[dt], 0, 0, 0);
      oacc[dt] = __builtin_amdgcn_mfma_f32_16x16x32_bf16(pa1, vf1, oacc[dt], 0, 0, 0);
    }
  }
  for (int rr = 0; rr < 4; ++rr)
    for (int msk = 8; msk; msk >>= 1) denom[rr] += __shfl_xor(denom[rr], msk, 64);
  for (int rr = 0; rr < 4; ++rr) {
    float rinv = 1.f / denom[rr];
    int sp = qt * 128 + w * 16 + ((lane >> 4) << 2) + rr;
    size_t orow = ((size_t)b * 1024 + sp) * 1024 + h * 64;
    for (int dt = 0; dt < 4; ++dt)
      obuf[orow + dt * 16 + (lane & 15)] = f2bf(oacc[dt][rr] * rinv);
  }
}

extern "C" void kernel_launch(void* const* d_in, const int* in_sizes, int n_in,
                              void* d_out, int out_size, void* d_ws, size_t ws_size,
                              hipStream_t stream) {
  const float* x = (const float*)d_in[0];
  const float* pos = (const float*)d_in[1];
  const float* cond = (const float*)d_in[2];
  const float* norm_scale = (const float*)d_in[3];
  const float* ada_w = (const float*)d_in[4];
  const float* ada_b = (const float*)d_in[5];
  const float* qkv_w = (const float*)d_in[6];
  const float* attn_scale = (const float*)d_in[7];
  const float* out_w = (const float*)d_in[8];
  const float* freqs = (const float*)d_in[9];
  float* out = (float*)d_out;
  char* ws = (char*)d_ws;
  float* mod = (float*)(ws + 0);                  //  49,152
  uint16_t* xm = (uint16_t*)(ws + 65536);         //   8 MB
  uint16_t* qkvw_bf = (uint16_t*)(ws + 8454144);  //   6 MB
  uint16_t* outw_bf = (uint16_t*)(ws + 14745600); //   2 MB
  uint16_t* qkv = (uint16_t*)(ws + 16842752);     //  24 MB
  uint16_t* Qb = (uint16_t*)(ws + 42008576);      //   8 MB
  uint16_t* Kb = (uint16_t*)(ws + 50397184);      //   8 MB
  uint16_t* Vt = (uint16_t*)(ws + 58785792);      //   8 MB
  uint16_t* obuf = (uint16_t*)(ws + 67174400);    //   8 MB

  k_prep<<<dim3(4096), dim3(256), 0, stream>>>(qkv_w, qkvw_bf, out_w, outw_bf,
                                               cond, ada_w, ada_b, mod);
  k_norm_mod<<<dim3(4096), dim3(256), 0, stream>>>(x, norm_scale, mod, xm);
  k_gemm<3072, 0><<<dim3(24, 32), dim3(256), 0, stream>>>(xm, qkvw_bf, qkv, nullptr, nullptr, nullptr);
  k_qkvpost<<<dim3(16, 64), dim3(256), 0, stream>>>(qkv, pos, freqs, attn_scale, Qb, Kb, Vt);
  k_attn<<<dim3(64, 8), dim3(512), 0, stream>>>(Qb, Kb, Vt, obuf);
  k_gemm<1024, 1><<<dim3(8, 32), dim3(256), 0, stream>>>(obuf, outw_bf, nullptr, x, mod, out);
}